// Round 1
// baseline (620.046 us; speedup 1.0000x reference)
//
#include <hip/hip_runtime.h>
#include <hip/hip_bf16.h>

#define NROWS 8192
#define DDIM 768

typedef short short8 __attribute__((ext_vector_type(8)));   // 8 x bf16 (4 VGPRs)
typedef float floatx4 __attribute__((ext_vector_type(4)));  // MFMA C/D
typedef float f4 __attribute__((ext_vector_type(4)));       // vector float4 (nt-loadable)
#define TSTRIDE 132   // transpose LDS row stride (floats): 2-way banks, 16B aligned

// ---------------------------------------------------------------------------
// Kernel 1: row-normalize features (fp32 in) -> bf16 normalized rows
// ---------------------------------------------------------------------------
__global__ __launch_bounds__(256) void normalize_k(const float* __restrict__ f,
                                                   __hip_bfloat16* __restrict__ fn) {
    const int row = blockIdx.x;
    const int t = threadIdx.x;
    const float* fr = f + (size_t)row * DDIM;
    float v0 = fr[t];
    float v1 = fr[t + 256];
    float v2 = fr[t + 512];
    float ss = v0 * v0 + v1 * v1 + v2 * v2;
#pragma unroll
    for (int m = 32; m; m >>= 1) ss += __shfl_xor(ss, m, 64);
    __shared__ float wsum[4];
    if ((t & 63) == 0) wsum[t >> 6] = ss;
    __syncthreads();
    float tot = wsum[0] + wsum[1] + wsum[2] + wsum[3];
    float inv = 1.0f / fmaxf(sqrtf(tot), 1e-8f);
    __hip_bfloat16* o = fn + (size_t)row * DDIM;
    o[t]       = __float2bfloat16(v0 * inv);
    o[t + 256] = __float2bfloat16(v1 * inv);
    o[t + 512] = __float2bfloat16(v2 * inv);
}

// ---------------------------------------------------------------------------
// Kernel 2: SYMMETRIC bf16 GEMM (s = 10 * fn fn^T) + fused mask reductions.
// Upper-triangle tiles only (2080 blocks, c<=r); off-diagonal blocks also run
// a mirror epilogue via the staging-LDS transpose.
// R9 changes vs R8 (K-loop math, epilogue math bit-identical):
//  (a) XCD-chunked block swizzle: consecutive triangle indices (same r-run)
//      land on the same XCD -> Js fn-tile served from that XCD's L2 instead
//      of 8x L3 fetches.
//  (b) Double-buffered staging with counted s_waitcnt vmcnt(4) + raw
//      s_barrier: K-step k+1's global_load_lds issued before computing k;
//      the barrier wait is for data issued a full step earlier (T3/T4
//      minimum pattern) instead of a vmcnt(0) drain every step.
//      LDS 16.9 -> 32.8 KB; occupancy is register-bound (acc=64 AGPR ->
//      ~128 unified regs -> 4 blocks/CU), so the extra LDS is free.
//  (c) Non-temporal loads for all mask traffic (streamed once, no reuse):
//      keeps fn resident in L2/L3.
// ---------------------------------------------------------------------------
__global__ __launch_bounds__(256, 4) void ntxent_main(
        const __hip_bfloat16* __restrict__ fn,
        const float* __restrict__ pmask, const float* __restrict__ nmask,
        float* __restrict__ negG, float* __restrict__ sG,
        float* __restrict__ pG) {
    __shared__ __align__(16) char smem[2 * 16384];          // 32 KB staging dbuf
    float* T = (float*)smem;                                // mirror transpose aliases

    const int t = threadIdx.x;
    const int lane = t & 63;
    const int wv = t >> 6;
    const int wm = wv & 1;           // wave's j-half
    const int wn = wv >> 1;          // wave's i-half
    const int q  = lane >> 4;
    const int cl = lane & 15;

    // XCD-chunked swizzle (2080 = 8 * 260, bijective): XCD x gets triangle
    // indices [x*260, (x+1)*260) -> resident blocks share r-runs -> Js L2 hits
    const int bt0 = blockIdx.x;
    const int bt = (bt0 & 7) * 260 + (bt0 >> 3);

    // triangular decode: block bt -> (c, r) with c <= r
    int r = (int)((sqrtf(8.0f * (float)bt + 1.0f) - 1.0f) * 0.5f);
    while ((r + 1) * (r + 2) / 2 <= bt) ++r;
    while (r * (r + 1) / 2 > bt) --r;
    const int c = bt - r * (r + 1) / 2;
    const int rowBase = c * 128;     // i-tile
    const int colBase = r * 128;     // j-tile
    const bool offDiag = (c != r);

    const int rdSw = ((q ^ ((cl >> 1) & 3)) << 4);

    floatx4 acc[4][4];            // [mf (j)][nf (i)]
#pragma unroll
    for (int mf = 0; mf < 4; ++mf)
#pragma unroll
        for (int nf = 0; nf < 4; ++nf)
            acc[mf][nf] = (floatx4){0.f, 0.f, 0.f, 0.f};

    // staging: 4 global_load_lds (16B) per thread per call, wave-linear LDS dest
    auto stage = [&](int buf, int k0) {
        char* isb = smem + buf * 16384;
#pragma unroll
        for (int it = 0; it < 2; ++it) {
            const int s = it * 256 + t;              // 16B slot 0..511
            const int rr = s >> 2;
            const int cg = (s & 3) ^ ((rr >> 1) & 3); // swizzled src chunk
            const __hip_bfloat16* ga = fn + (size_t)(rowBase + rr) * DDIM + k0 + cg * 8;
            const __hip_bfloat16* gb = fn + (size_t)(colBase + rr) * DDIM + k0 + cg * 8;
            __builtin_amdgcn_global_load_lds(
                (const __attribute__((address_space(1))) void*)ga,
                (__attribute__((address_space(3))) void*)(isb + s * 16), 16, 0, 0);
            __builtin_amdgcn_global_load_lds(
                (const __attribute__((address_space(1))) void*)gb,
                (__attribute__((address_space(3))) void*)(isb + 8192 + s * 16), 16, 0, 0);
        }
    };

    stage(0, 0);                                     // prologue: K-step 0
    for (int kt = 0; kt < 24; ++kt) {
        const int cur = kt & 1;
        if (kt < 23) {
            stage(cur ^ 1, (kt + 1) * 32);           // prefetch next K-step
            // wait only the CURRENT buffer's 4 loads (issued last iter);
            // the 4 just-issued prefetch loads stay in flight across barrier
            asm volatile("s_waitcnt vmcnt(4)\n\ts_barrier" ::: "memory");
        } else {
            asm volatile("s_waitcnt vmcnt(0)\n\ts_barrier" ::: "memory");
        }

        const char* IsC = smem + cur * 16384;
        const char* JsC = IsC + 8192;
        short8 jf[4], if_[4];
#pragma unroll
        for (int mf = 0; mf < 4; ++mf) {
            const int rr = wm * 64 + mf * 16 + cl;
            jf[mf] = *(const short8*)(JsC + rr * 64 + rdSw);
        }
#pragma unroll
        for (int nf = 0; nf < 4; ++nf) {
            const int rr = wn * 64 + nf * 16 + cl;
            if_[nf] = *(const short8*)(IsC + rr * 64 + rdSw);
        }
#pragma unroll
        for (int mf = 0; mf < 4; ++mf)
#pragma unroll
            for (int nf = 0; nf < 4; ++nf)
                acc[mf][nf] = __builtin_amdgcn_mfma_f32_16x16x32_bf16(
                    jf[mf], if_[nf], acc[mf][nf], 0, 0, 0);

        // all waves done reading buf[cur] before next iter's stage overwrites it
        asm volatile("s_barrier" ::: "memory");
    }

    // ---- direct epilogue (rows i, mask[i][j]) ----
    const int col64 = colBase + wm * 64;
    const int jb0 = col64 + q * 4;
#pragma unroll
    for (int nf = 0; nf < 4; ++nf) {
        const int grow = rowBase + wn * 64 + nf * 16 + cl;
        const float* prow = pmask + (size_t)grow * NROWS;
        const float* nrow = nmask + (size_t)grow * NROWS;
        f4 pm4[4], nm4[4];
#pragma unroll
        for (int mf = 0; mf < 4; ++mf) {
            pm4[mf] = __builtin_nontemporal_load((const f4*)(prow + jb0 + mf * 16));
            nm4[mf] = __builtin_nontemporal_load((const f4*)(nrow + jb0 + mf * 16));
        }
        float aN = 0.f, aS = 0.f, aP = 0.f;
#pragma unroll
        for (int mf = 0; mf < 4; ++mf) {
            const int jbase = jb0 + mf * 16;
#pragma unroll
            for (int reg = 0; reg < 4; ++reg) {
                float pmv = pm4[mf][reg];
                float nmv = nm4[mf][reg];
                if (grow == jbase + reg) { pmv = 0.f; nmv = 0.f; }  // diagonal
                float v = acc[mf][nf][reg];
                float e = __builtin_amdgcn_exp2f(v * 14.4269504089f); // e^(10v)
                aN = fmaf(nmv, e, aN);
                aS = fmaf(pmv, v, aS);       // raw acc units; x10 in final_k
                aP += pmv;
            }
        }
        aN += __shfl_xor(aN, 16, 64);  aN += __shfl_xor(aN, 32, 64);
        aS += __shfl_xor(aS, 16, 64);  aS += __shfl_xor(aS, 32, 64);
        aP += __shfl_xor(aP, 16, 64);  aP += __shfl_xor(aP, 32, 64);
        if (q == 0) {
            atomicAdd(&negG[grow], aN);
            atomicAdd(&sG[grow],   aS);
            atomicAdd(&pG[grow],   aP);
        }
    }

    // ---- mirror epilogue (rows j, mask[j][i]) -- off-diagonal blocks only --
    if (offDiag) {
        const int jl2 = t >> 3;              // 0..31: strip-local j row
        const int iseg = (t & 7) * 16;       // 16-float i segment
#pragma unroll
        for (int st = 0; st < 4; ++st) {
            __syncthreads();                 // strip buffer free
            if (wm == (st >> 1)) {           // waves owning this strip's j's
#pragma unroll
                for (int m2 = 0; m2 < 2; ++m2) {
                    const int mf = (st & 1) * 2 + m2;
#pragma unroll
                    for (int nf = 0; nf < 4; ++nf) {
                        const int i = wn * 64 + nf * 16 + cl;
#pragma unroll
                        for (int reg = 0; reg < 4; ++reg) {
                            const int jl = m2 * 16 + q * 4 + reg;
                            T[jl * TSTRIDE + i] = acc[mf][nf][reg];
                        }
                    }
                }
            }
            __syncthreads();
            const int jg = colBase + st * 32 + jl2;
            const float* prow = pmask + (size_t)jg * NROWS + rowBase + iseg;
            const float* nrow = nmask + (size_t)jg * NROWS + rowBase + iseg;
            f4 pm4[4], nm4[4];
#pragma unroll
            for (int u = 0; u < 4; ++u) {
                pm4[u] = __builtin_nontemporal_load((const f4*)(prow + u * 4));
                nm4[u] = __builtin_nontemporal_load((const f4*)(nrow + u * 4));
            }
            const f4* tv = (const f4*)(T + jl2 * TSTRIDE + iseg);
            float aN = 0.f, aS = 0.f, aP = 0.f;
#pragma unroll
            for (int u = 0; u < 4; ++u) {
                f4 v4 = tv[u];
#pragma unroll
                for (int e = 0; e < 4; ++e) {
                    float v = v4[e];
                    float pmv = pm4[u][e];
                    float nmv = nm4[u][e];
                    float ex = __builtin_amdgcn_exp2f(v * 14.4269504089f);
                    aN = fmaf(nmv, ex, aN);
                    aS = fmaf(pmv, v, aS);
                    aP += pmv;
                }
            }
            aN += __shfl_xor(aN, 1, 64); aN += __shfl_xor(aN, 2, 64); aN += __shfl_xor(aN, 4, 64);
            aS += __shfl_xor(aS, 1, 64); aS += __shfl_xor(aS, 2, 64); aS += __shfl_xor(aS, 4, 64);
            aP += __shfl_xor(aP, 1, 64); aP += __shfl_xor(aP, 2, 64); aP += __shfl_xor(aP, 4, 64);
            if ((t & 7) == 0) {
                atomicAdd(&negG[jg], aN);
                atomicAdd(&sG[jg],   aS);
                atomicAdd(&pG[jg],   aP);
            }
        }
    }
}

// ---------------------------------------------------------------------------
// Kernel 3: per-row loss assembly + mean
// loss_i = (P*log(neg) - 10*S_raw)/P (P>0 else 0);  out = mean
// ---------------------------------------------------------------------------
__global__ __launch_bounds__(1024) void final_k(const float* __restrict__ negG,
        const float* __restrict__ sG, const float* __restrict__ pG,
        float* __restrict__ out) {
    const int t = threadIdx.x;
    float sum = 0.f;
    for (int i = t; i < NROWS; i += 1024) {
        float P = pG[i];
        if (P > 0.f) {
            sum += (P * logf(negG[i]) - 10.0f * sG[i]) / P;
        }
    }
#pragma unroll
    for (int m = 32; m; m >>= 1) sum += __shfl_xor(sum, m, 64);
    __shared__ float wsum[16];
    if ((t & 63) == 0) wsum[t >> 6] = sum;
    __syncthreads();
    if (t < 16) {
        float v = wsum[t];
#pragma unroll
        for (int m = 8; m; m >>= 1) v += __shfl_xor(v, m, 16);
        if (t == 0) out[0] = v / (float)NROWS;
    }
}

// ---------------------------------------------------------------------------
extern "C" void kernel_launch(void* const* d_in, const int* in_sizes, int n_in,
                              void* d_out, int out_size, void* d_ws, size_t ws_size,
                              hipStream_t stream) {
    const float* feat  = (const float*)d_in[0];
    const float* pmask = (const float*)d_in[1];
    const float* nmask = (const float*)d_in[2];
    float* out = (float*)d_out;

    char* ws = (char*)d_ws;
    __hip_bfloat16* fn = (__hip_bfloat16*)ws;                    // 12,582,912 B
    float* negG = (float*)(ws + 12582912);
    float* sG = negG + NROWS;
    float* pG = sG + NROWS;

    // zero all three row accumulators (ws is re-poisoned before every launch)
    hipMemsetAsync(negG, 0, 3 * NROWS * sizeof(float), stream);

    normalize_k<<<NROWS, 256, 0, stream>>>(feat, fn);

    ntxent_main<<<2080, 256, 0, stream>>>(fn, pmask, nmask, negG, sG, pG);

    final_k<<<1, 1024, 0, stream>>>(negG, sG, pG, out);
}